// Round 9
// baseline (44.340 us; speedup 1.0000x reference)
//
#include <hip/hip_runtime.h>
#include <math.h>

#define NC 80
#define NA 3
#define BATCH 16
#define NGT 32
#define IOU_THR 0.5f
#define FEPS 1e-7f

#define ASSIGN_BLOCKS 48               // one per (batch, scale), bid 0..47
#define OBJ_BLOCKS 525                 // 400(s0)+100(s1)+25(s2), 768 contiguous cells each
#define GRID (ASSIGN_BLOCKS + OBJ_BLOCKS)   // 573  (~2.05 blocks/CU -> 2 waves/SIMD)
#define OBJ_PER_BLOCK 768              // = 3 * 256: exactly 3 independent loads/thread
#define OBJ_J1 400
#define OBJ_J2 500

// ws layout: block bid owns the FULL 128B line at SLOT(bid) exclusively
// (per-XCD L2s not cross-coherent; never share a line between writer blocks).
// All slots written unconditionally every call -> no memset/atomics/fences.
// Kernel-boundary release/acquire makes them visible to final_kernel (R3/R7/R8-proven).
#define SLOT(bid) (32 * (bid))

__device__ __forceinline__ float bce_f(float x, float t) {
    return fmaxf(x, 0.f) - x * t + log1pf(expf(-fabsf(x)));
}

__global__ __launch_bounds__(256) void det_loss_kernel(
    const float* __restrict__ p0, const float* __restrict__ p1, const float* __restrict__ p2,
    const float* __restrict__ a0, const float* __restrict__ a1, const float* __restrict__ a2,
    const float* __restrict__ gt_boxes, const int* __restrict__ gt_labels,
    float* __restrict__ ws_f)
{
    const int bid = blockIdx.x;
    const int t = threadIdx.x;
    const int lane = t & 63, wv = t >> 6;
    __shared__ float red[4][4];

    if (bid >= ASSIGN_BLOCKS) {
        // ==== obj noobj-base sweep: 768 contiguous cells, 3 unrolled independent loads ====
        const int j = bid - ASSIGN_BLOCKS;
        const float* p; int base;
        if (j < OBJ_J1)      { p = p0; base = j * OBJ_PER_BLOCK; }
        else if (j < OBJ_J2) { p = p1; base = (j - OBJ_J1) * OBJ_PER_BLOCK; }
        else                 { p = p2; base = (j - OBJ_J2) * OBJ_PER_BLOCK; }
        // issue all 3 loads before consuming any (independent addresses -> 3-deep MLP)
        float x0 = p[(size_t)(base + t)       * (5 + NC) + 4];
        float x1 = p[(size_t)(base + t + 256) * (5 + NC) + 4];
        float x2 = p[(size_t)(base + t + 512) * (5 + NC) + 4];
        float acc = 0.5f * (bce_f(x0, 0.f) + bce_f(x1, 0.f) + bce_f(x2, 0.f));
        #pragma unroll
        for (int off = 32; off; off >>= 1) acc += __shfl_down(acc, off);
        if (lane == 0) red[0][wv] = acc;
        __syncthreads();
        if (t == 0)
            ws_f[SLOT(bid)] = red[0][0] + red[0][1] + red[0][2] + red[0][3];
        return;
    }

    // ============ assignment + positive losses (one block per (b, si)) ============
    const int si = bid % 3;
    const int b  = bid / 3;
    const int W  = 80 >> si;
    const int HW = W * W;
    const float s = (float)(8 << si);
    const float* anch = (si == 0) ? a0 : (si == 1) ? a1 : a2;
    const float* p    = (si == 0) ? p0 : (si == 1) ? p1 : p2;

    __shared__ float gtb[NGT][4];
    __shared__ int   gflat[NGT];
    __shared__ float giou[NA][NGT];
    __shared__ float gcand[NA][NGT];
    __shared__ unsigned char gpos[NA][NGT];
    __shared__ unsigned char gisb[NA][NGT];
    __shared__ int wlist[NA * NGT];
    __shared__ int wcnt[4];
    __shared__ int s_wn;

    if (t < 128) gtb[t >> 2][t & 3] = gt_boxes[b * NGT * 4 + t];
    __syncthreads();

    if (t < NGT) {
        float x1 = gtb[t][0], y1 = gtb[t][1], x2 = gtb[t][2], y2 = gtb[t][3];
        float gcx = (x1 + x2) * 0.5f, gcy = (y1 + y2) * 0.5f;
        int gx = (int)(gcx / s); gx = min(max(gx, 0), W - 1);
        int gy = (int)(gcy / s); gy = min(max(gy, 0), W - 1);
        gflat[t] = gy * W + gx;
    }
    __syncthreads();

    if (t < NA * NGT) {
        int a = t >> 5, n = t & 31;
        int flat = gflat[n];
        const float* ap = anch + ((size_t)a * HW + flat) * 4;
        float acx = ap[0], acy = ap[1], aw = ap[2], ah = ap[3];
        float ax1 = acx - aw * 0.5f, ay1 = acy - ah * 0.5f;
        float ax2 = acx + aw * 0.5f, ay2 = acy + ah * 0.5f;
        float x1 = gtb[n][0], y1 = gtb[n][1], x2 = gtb[n][2], y2 = gtb[n][3];
        float iw = fmaxf(fminf(x2, ax2) - fmaxf(x1, ax1), 0.f);
        float ih = fmaxf(fminf(y2, ay2) - fmaxf(y1, ay1), 0.f);
        float inter = iw * ih;
        float a_gt = (x2 - x1) * (y2 - y1);
        float a_an = aw * ah;
        giou[a][n] = inter / (a_gt + a_an - inter + FEPS);
    }
    __syncthreads();

    if (t < NA * NGT) {
        int a = t >> 5, n = t & 31;
        float i0 = giou[0][n], i1 = giou[1][n], i2 = giou[2][n];
        bool has = (i0 > IOU_THR) || (i1 > IOU_THR) || (i2 > IOU_THR);
        int amax = 0; float bv = i0;                // first-max like jnp.argmax
        if (i1 > bv) { bv = i1; amax = 1; }
        if (i2 > bv) { bv = i2; amax = 2; }
        float iou = giou[a][n];
        bool ps = has ? (iou > IOU_THR) : (a == amax);
        gpos[a][n] = ps ? 1 : 0;
        gcand[a][n] = ps ? iou : -1.0f;
    }
    __syncthreads();

    if (t < NA * NGT) {
        int a = t >> 5, n = t & 31;
        int flat = gflat[n];
        float best = -1.0f;                         // scatter-max init
        for (int m = 0; m < NGT; ++m)
            if (gflat[m] == flat) best = fmaxf(best, gcand[a][m]);
        gisb[a][n] = (gpos[a][n] && gcand[a][n] >= best) ? 1 : 0;
    }
    __syncthreads();

    // winner detection + ballot-compacted LDS list
    int win = 0, pack = 0;
    if (t < NA * NGT) {
        int a = t >> 5, n = t & 31;
        if (gisb[a][n]) {
            int flat = gflat[n];
            bool first = true;                      // win = min gt index among isb
            for (int m = 0; m < n; ++m)
                if (gflat[m] == flat && gisb[a][m]) { first = false; break; }
            if (first) { win = 1; pack = flat | (a << 13) | (n << 19); }
        }
    }
    unsigned long long mask = __ballot(win);
    if (lane == 0) wcnt[wv] = (int)__popcll(mask);
    __syncthreads();
    if (win) {
        int base = 0;
        for (int w2 = 0; w2 < wv; ++w2) base += wcnt[w2];
        int idx = base + (int)__popcll(mask & ((1ull << lane) - 1ull));
        wlist[idx] = pack;
    }
    if (t == 0) s_wn = wcnt[0] + wcnt[1] + wcnt[2] + wcnt[3];
    __syncthreads();
    const int wn = s_wn;

    // positive losses: 2 lanes per cell -> all <=96 winners in ONE pass
    float v_box = 0.f, v_nv = 0.f, v_cls = 0.f, v_obj = 0.f;
    const int cell = t >> 1, l2 = t & 1;
    if (cell < wn) {
        int e = wlist[cell];
        int flat = e & 0x1FFF;
        int a = (e >> 13) & 3;
        int n = (e >> 19) & 31;
        const float* pred = p + (size_t)((b * NA + a) * HW + flat) * (5 + NC);

        // cls BCE: 40 channels per lane, pair-interleaved
        int label = gt_labels[b * NGT + n];
        float csum = 0.f;
        #pragma unroll 8
        for (int jj = 0; jj < 40; ++jj) {
            int c = l2 + 2 * jj;
            float x = pred[5 + c];
            csum += bce_f(x, (c == label) ? 1.f : 0.f);
        }
        csum += __shfl_xor(csum, 1);

        // decode + ciou (redundant on 2 lanes; l2==0 accumulates)
        const float* ap = anch + ((size_t)a * HW + flat) * 4;
        float acx = ap[0], acy = ap[1], aw = ap[2], ah = ap[3];
        float s0 = 1.f / (1.f + expf(-pred[0]));
        float s1 = 1.f / (1.f + expf(-pred[1]));
        float s2 = 1.f / (1.f + expf(-pred[2]));
        float s3 = 1.f / (1.f + expf(-pred[3]));
        float cx = acx + (s0 * 2.f - 0.5f) * s;
        float cy = acy + (s1 * 2.f - 0.5f) * s;
        float pw = aw * (s2 * 2.f) * (s2 * 2.f);
        float ph = ah * (s3 * 2.f) * (s3 * 2.f);
        float b1x1 = cx - pw * 0.5f, b1y1 = cy - ph * 0.5f;
        float b1x2 = cx + pw * 0.5f, b1y2 = cy + ph * 0.5f;
        float b2x1 = gtb[n][0], b2y1 = gtb[n][1];
        float b2x2 = gtb[n][2], b2y2 = gtb[n][3];

        float w1 = b1x2 - b1x1, h1 = b1y2 - b1y1;
        float w2 = b2x2 - b2x1, h2 = b2y2 - b2y1;
        float iw = fmaxf(fminf(b1x2, b2x2) - fmaxf(b1x1, b2x1), 0.f);
        float ih = fmaxf(fminf(b1y2, b2y2) - fmaxf(b1y1, b2y1), 0.f);
        float inter = iw * ih;
        float uni = w1 * h1 + w2 * h2 - inter + FEPS;
        float iou = inter / uni;
        float cw = fmaxf(b1x2, b2x2) - fminf(b1x1, b2x1);
        float ch = fmaxf(b1y2, b2y2) - fminf(b1y1, b2y1);
        float c2 = cw * cw + ch * ch + FEPS;
        float dx = b2x1 + b2x2 - b1x1 - b1x2;
        float dy = b2y1 + b2y2 - b1y1 - b1y2;
        float rho2 = (dx * dx + dy * dy) * 0.25f;
        const float PI = 3.14159265358979323846f;
        float dv = atanf(w2 / (h2 + FEPS)) - atanf(w1 / (h1 + FEPS));
        float v = (4.f / (PI * PI)) * dv * dv;
        float alpha = v / (v - iou + (1.f + FEPS));
        float ciou = iou - rho2 / c2 - alpha * v;

        if (l2 == 0) {
            if (isfinite(ciou)) { v_box = 1.f - ciou; v_nv = 1.f; }
            v_cls = csum;
            float ox = pred[4];
            v_obj = bce_f(ox, 1.f) - 0.5f * bce_f(ox, 0.f);
        }
    }

    #pragma unroll
    for (int off = 32; off; off >>= 1) {
        v_box += __shfl_down(v_box, off);
        v_nv  += __shfl_down(v_nv,  off);
        v_cls += __shfl_down(v_cls, off);
        v_obj += __shfl_down(v_obj, off);
    }
    if (lane == 0) { red[0][wv] = v_box; red[1][wv] = v_nv; red[2][wv] = v_cls; red[3][wv] = v_obj; }
    __syncthreads();
    if (t == 0) {
        float* slot = ws_f + SLOT(bid);
        slot[0] = red[0][0] + red[0][1] + red[0][2] + red[0][3];
        slot[1] = red[1][0] + red[1][1] + red[1][2] + red[1][3];
        slot[2] = red[2][0] + red[2][1] + red[2][2] + red[2][3];
        slot[3] = red[3][0] + red[3][1] + red[3][2] + red[3][3];
        slot[4] = (float)wn;
    }
}

__global__ __launch_bounds__(256) void final_kernel(const float* __restrict__ ws_f,
                                                    float* __restrict__ out)
{
    const int t = threadIdx.x;
    const int lane = t & 63, wv = t >> 6;
    __shared__ float red[4][4];
    __shared__ float sc[3][6];   // per scale: box, nv, cls, obj_corr, np, obj_base

    // obj-base partials: 525 slots, scale by block index range
    float o0 = 0.f, o1 = 0.f, o2 = 0.f;
    for (int j = t; j < OBJ_BLOCKS; j += 256) {
        float v = ws_f[SLOT(ASSIGN_BLOCKS + j)];
        if (j < OBJ_J1) o0 += v; else if (j < OBJ_J2) o1 += v; else o2 += v;
    }
    #pragma unroll
    for (int off = 32; off; off >>= 1) {
        o0 += __shfl_down(o0, off);
        o1 += __shfl_down(o1, off);
        o2 += __shfl_down(o2, off);
    }
    if (lane == 0) { red[0][wv] = o0; red[1][wv] = o1; red[2][wv] = o2; }
    __syncthreads();
    if (t == 0) {
        sc[0][5] = red[0][0] + red[0][1] + red[0][2] + red[0][3];
        sc[1][5] = red[1][0] + red[1][1] + red[1][2] + red[1][3];
        sc[2][5] = red[2][0] + red[2][1] + red[2][2] + red[2][3];
    }

    // assign partials: wave wv owns scale wv; 16 lanes x 16 batches
    float b_ = 0.f, nv_ = 0.f, c_ = 0.f, oc_ = 0.f, np_ = 0.f;
    if (wv < 3 && lane < 16) {
        const float* s3 = ws_f + SLOT(lane * 3 + wv);
        b_ = s3[0]; nv_ = s3[1]; c_ = s3[2]; oc_ = s3[3]; np_ = s3[4];
    }
    #pragma unroll
    for (int off = 8; off; off >>= 1) {     // lanes >=16 hold zeros
        b_  += __shfl_down(b_,  off);
        nv_ += __shfl_down(nv_, off);
        c_  += __shfl_down(c_,  off);
        oc_ += __shfl_down(oc_, off);
        np_ += __shfl_down(np_, off);
    }
    if (wv < 3 && lane == 0) {
        sc[wv][0] = b_; sc[wv][1] = nv_; sc[wv][2] = c_; sc[wv][3] = oc_; sc[wv][4] = np_;
    }
    __syncthreads();

    if (t == 0) {
        float bl = 0.f, ol = 0.f, cl = 0.f;
        int tv = 0;
        for (int s = 0; s < 3; ++s) {
            int Wd = 80 >> s;
            int total = BATCH * NA * Wd * Wd;
            float nv = sc[s][1], np = sc[s][4];
            bl += sc[s][0] / fmaxf(nv, 1.f);
            float wsum = np + 0.5f * ((float)total - np);
            ol += (sc[s][5] + sc[s][3]) / (wsum + 1e-6f);
            cl += sc[s][2] / fmaxf(np * (float)NC, 1.f);
            tv += (int)nv;
        }
        if (tv > 0) { bl /= 3.f; cl /= 3.f; }
        ol /= 3.f;
        float total = 0.15f * bl + 5.0f * ol + 0.5f * cl;
        out[0] = isfinite(total) ? total : 0.f;
    }
}

extern "C" void kernel_launch(void* const* d_in, const int* in_sizes, int n_in,
                              void* d_out, int out_size, void* d_ws, size_t ws_size,
                              hipStream_t stream) {
    const float* p0  = (const float*)d_in[0];
    const float* p1  = (const float*)d_in[1];
    const float* p2  = (const float*)d_in[2];
    const float* a0  = (const float*)d_in[3];
    const float* a1  = (const float*)d_in[4];
    const float* a2  = (const float*)d_in[5];
    const float* gtb = (const float*)d_in[6];
    const int*   gtl = (const int*)d_in[7];

    det_loss_kernel<<<GRID, 256, 0, stream>>>(
        p0, p1, p2, a0, a1, a2, gtb, gtl, (float*)d_ws);
    final_kernel<<<1, 256, 0, stream>>>((const float*)d_ws, (float*)d_out);
}

// Round 10
// 26.264 us; speedup vs baseline: 1.6883x; 1.6883x over previous
//
#include <hip/hip_runtime.h>
#include <math.h>

#define NC 80
#define NA 3
#define BATCH 16
#define NGT 32
#define IOU_THR 0.5f
#define FEPS 1e-7f

#define ASSIGN_GRID 48            // one block per (batch, scale): bid = b*3 + si
#define OBJ_BLOCKS 168            // 128(s0)+32(s1)+8(s2) x 2400 cells grid-stride (R2-exact)
#define POS_BLOCKS 288            // 6 sub-blocks per assign block; 16 lanes/cell (R2-exact)
#define LOSS_GRID (OBJ_BLOCKS + POS_BLOCKS)   // 456 (R2's proven grid shape)

// ws word layout — every slot written unconditionally each call (poison-proof):
//   A_SLOT(a):  128 words per assign block a: [0]=wn, [1..96]=packed list (0-padded)
//   OBJ_SLOT(j): 1 exclusive 128B line per obj block
//   POS_SLOT(j): 1 exclusive 128B line per pos block: box, nv, cls, obj_corr
#define A_SLOT(a)  (128 * (a))                    // 48*128 = 6144 words
#define OBJ_SLOT(j) (6144 + 32 * (j))             // +168*32 -> 11520
#define POS_SLOT(j) (11520 + 32 * (j))            // +288*32 -> 20736 words (83KB)

__device__ __forceinline__ float bce_f(float x, float t) {
    return fmaxf(x, 0.f) - x * t + log1pf(expf(-fabsf(x)));
}

__global__ __launch_bounds__(128) void assign_kernel(
    const float* __restrict__ gt_boxes,
    const float* __restrict__ a0, const float* __restrict__ a1, const float* __restrict__ a2,
    int* ws_i)
{
    const int bid = blockIdx.x;       // b*3 + si
    const int si = bid % 3;
    const int b  = bid / 3;
    const int W  = 80 >> si;
    const int HW = W * W;
    const float s = (float)(8 << si);
    const float* anch = (si == 0) ? a0 : (si == 1) ? a1 : a2;

    __shared__ float gtb[NGT][4];
    __shared__ int   gflat[NGT];
    __shared__ float giou[NA][NGT];
    __shared__ float gcand[NA][NGT];
    __shared__ unsigned char gpos[NA][NGT];
    __shared__ unsigned char gisb[NA][NGT];
    __shared__ int wlist[NA * NGT];
    __shared__ int wcnt2[2];
    __shared__ int s_wn;

    const int t = threadIdx.x;
    const int lane = t & 63, wv = t >> 6;
    gtb[t >> 2][t & 3] = gt_boxes[b * NGT * 4 + t];
    __syncthreads();

    if (t < NGT) {
        float x1 = gtb[t][0], y1 = gtb[t][1], x2 = gtb[t][2], y2 = gtb[t][3];
        float gcx = (x1 + x2) * 0.5f, gcy = (y1 + y2) * 0.5f;
        int gx = (int)(gcx / s); gx = min(max(gx, 0), W - 1);
        int gy = (int)(gcy / s); gy = min(max(gy, 0), W - 1);
        gflat[t] = gy * W + gx;
    }
    __syncthreads();

    if (t < NA * NGT) {
        int a = t >> 5, n = t & 31;
        int flat = gflat[n];
        const float* ap = anch + ((size_t)a * HW + flat) * 4;
        float acx = ap[0], acy = ap[1], aw = ap[2], ah = ap[3];
        float ax1 = acx - aw * 0.5f, ay1 = acy - ah * 0.5f;
        float ax2 = acx + aw * 0.5f, ay2 = acy + ah * 0.5f;
        float x1 = gtb[n][0], y1 = gtb[n][1], x2 = gtb[n][2], y2 = gtb[n][3];
        float iw = fmaxf(fminf(x2, ax2) - fmaxf(x1, ax1), 0.f);
        float ih = fmaxf(fminf(y2, ay2) - fmaxf(y1, ay1), 0.f);
        float inter = iw * ih;
        float a_gt = (x2 - x1) * (y2 - y1);
        float a_an = aw * ah;
        giou[a][n] = inter / (a_gt + a_an - inter + FEPS);
    }
    __syncthreads();

    if (t < NA * NGT) {
        int a = t >> 5, n = t & 31;
        float i0 = giou[0][n], i1 = giou[1][n], i2 = giou[2][n];
        bool has = (i0 > IOU_THR) || (i1 > IOU_THR) || (i2 > IOU_THR);
        int amax = 0; float bv = i0;                // first-max like jnp.argmax
        if (i1 > bv) { bv = i1; amax = 1; }
        if (i2 > bv) { bv = i2; amax = 2; }
        float iou = giou[a][n];
        bool ps = has ? (iou > IOU_THR) : (a == amax);
        gpos[a][n] = ps ? 1 : 0;
        gcand[a][n] = ps ? iou : -1.0f;
    }
    __syncthreads();

    if (t < NA * NGT) {
        int a = t >> 5, n = t & 31;
        int flat = gflat[n];
        float best = -1.0f;                         // scatter-max init
        for (int m = 0; m < NGT; ++m)
            if (gflat[m] == flat) best = fmaxf(best, gcand[a][m]);
        gisb[a][n] = (gpos[a][n] && gcand[a][n] >= best) ? 1 : 0;
    }
    __syncthreads();

    // winner detection + ballot-compacted list (no atomics)
    int win = 0, pack = 0;
    if (t < NA * NGT) {
        int a = t >> 5, n = t & 31;
        if (gisb[a][n]) {
            int flat = gflat[n];
            bool first = true;                      // win = min gt index among isb
            for (int m = 0; m < n; ++m)
                if (gflat[m] == flat && gisb[a][m]) { first = false; break; }
            if (first) { win = 1; pack = flat | (a << 13) | (n << 19); }
        }
    }
    unsigned long long mask = __ballot(win);
    if (lane == 0) wcnt2[wv] = (int)__popcll(mask);
    __syncthreads();
    if (win) {
        int base = wv ? wcnt2[0] : 0;
        int idx = base + (int)__popcll(mask & ((1ull << lane) - 1ull));
        wlist[idx] = pack;
    }
    if (t == 0) s_wn = wcnt2[0] + wcnt2[1];
    __syncthreads();
    const int wn = s_wn;

    int* slot = ws_i + A_SLOT(bid);
    if (t == 0) slot[0] = wn;
    if (t < 96) slot[1 + t] = (t < wn) ? wlist[t] : 0;   // all 97 words written
}

__global__ __launch_bounds__(256) void loss_kernel(
    const float* __restrict__ p0, const float* __restrict__ p1, const float* __restrict__ p2,
    const float* __restrict__ a0, const float* __restrict__ a1, const float* __restrict__ a2,
    const float* __restrict__ gt_boxes, const int* __restrict__ gt_labels,
    float* ws_f, const int* ws_i)
{
    const int bid = blockIdx.x;
    const int t = threadIdx.x;
    const int lane = t & 63, wv = t >> 6;
    __shared__ float red[4][4];

    if (bid < OBJ_BLOCKS) {
        // ---- noobj base sweep (R2-exact): 2400 cells grid-stride ----
        int si, blk_local; const float* p;
        if (bid < 128)      { si = 0; blk_local = bid;       p = p0; }
        else if (bid < 160) { si = 1; blk_local = bid - 128; p = p1; }
        else                { si = 2; blk_local = bid - 160; p = p2; }
        int base_e = blk_local * 2400;
        float acc = 0.f;
        #pragma unroll 2
        for (int i = t; i < 2400; i += 256) {
            float x = p[(size_t)(base_e + i) * (5 + NC) + 4];
            acc += 0.5f * bce_f(x, 0.f);
        }
        #pragma unroll
        for (int off = 32; off; off >>= 1) acc += __shfl_down(acc, off);
        if (lane == 0) red[0][wv] = acc;
        __syncthreads();
        if (t == 0)
            ws_f[OBJ_SLOT(bid)] = red[0][0] + red[0][1] + red[0][2] + red[0][3];
        return;
    }

    // ---- positive-cell losses (R2-exact body): 16 lanes per cell ----
    const int pbid = bid - OBJ_BLOCKS;     // [0, 288)
    const int g48 = pbid / 6;              // owning assign block (b*3+si)
    const int sub = pbid % 6;
    const int si = g48 % 3;
    const int b  = g48 / 3;
    const int W  = 80 >> si;
    const int HW = W * W;
    const float s = (float)(8 << si);
    const float* p    = (si == 0) ? p0 : (si == 1) ? p1 : p2;
    const float* anch = (si == 0) ? a0 : (si == 1) ? a1 : a2;
    const int* aslot = ws_i + A_SLOT(g48);
    const int wn = aslot[0];

    const int g16 = t >> 4, l16 = t & 15;
    const int cell = sub * 16 + g16;
    float v_box = 0.f, v_nv = 0.f, v_cls = 0.f, v_obj = 0.f;
    if (cell < wn) {
        int e = aslot[1 + cell];
        int flat = e & 0x1FFF;
        int a = (e >> 13) & 3;
        int n = (e >> 19) & 31;
        const float* pred = p + (size_t)((b * NA + a) * HW + flat) * (5 + NC);

        // cls BCE: 5 coalesced channels per lane
        int label = gt_labels[b * NGT + n];
        float csum = 0.f;
        #pragma unroll
        for (int jj = 0; jj < 5; ++jj) {
            int c = l16 + 16 * jj;
            float x = pred[5 + c];
            csum += bce_f(x, (c == label) ? 1.f : 0.f);
        }
        #pragma unroll
        for (int m = 8; m; m >>= 1) csum += __shfl_xor(csum, m);

        // decode + ciou (redundant on 16 lanes; lane 0 contributes)
        const float* ap = anch + ((size_t)a * HW + flat) * 4;
        float acx = ap[0], acy = ap[1], aw = ap[2], ah = ap[3];
        float s0 = 1.f / (1.f + expf(-pred[0]));
        float s1 = 1.f / (1.f + expf(-pred[1]));
        float s2 = 1.f / (1.f + expf(-pred[2]));
        float s3 = 1.f / (1.f + expf(-pred[3]));
        float cx = acx + (s0 * 2.f - 0.5f) * s;
        float cy = acy + (s1 * 2.f - 0.5f) * s;
        float pw = aw * (s2 * 2.f) * (s2 * 2.f);
        float ph = ah * (s3 * 2.f) * (s3 * 2.f);
        float b1x1 = cx - pw * 0.5f, b1y1 = cy - ph * 0.5f;
        float b1x2 = cx + pw * 0.5f, b1y2 = cy + ph * 0.5f;
        const float* gb = gt_boxes + (size_t)(b * NGT + n) * 4;
        float b2x1 = gb[0], b2y1 = gb[1], b2x2 = gb[2], b2y2 = gb[3];

        float w1 = b1x2 - b1x1, h1 = b1y2 - b1y1;
        float w2 = b2x2 - b2x1, h2 = b2y2 - b2y1;
        float iw = fmaxf(fminf(b1x2, b2x2) - fmaxf(b1x1, b2x1), 0.f);
        float ih = fmaxf(fminf(b1y2, b2y2) - fmaxf(b1y1, b2y1), 0.f);
        float inter = iw * ih;
        float uni = w1 * h1 + w2 * h2 - inter + FEPS;
        float iou = inter / uni;
        float cw = fmaxf(b1x2, b2x2) - fminf(b1x1, b2x1);
        float ch = fmaxf(b1y2, b2y2) - fminf(b1y1, b2y1);
        float c2 = cw * cw + ch * ch + FEPS;
        float dx = b2x1 + b2x2 - b1x1 - b1x2;
        float dy = b2y1 + b2y2 - b1y1 - b1y2;
        float rho2 = (dx * dx + dy * dy) * 0.25f;
        const float PI = 3.14159265358979323846f;
        float dv = atanf(w2 / (h2 + FEPS)) - atanf(w1 / (h1 + FEPS));
        float v = (4.f / (PI * PI)) * dv * dv;
        float alpha = v / (v - iou + (1.f + FEPS));
        float ciou = iou - rho2 / c2 - alpha * v;

        if (l16 == 0) {
            if (isfinite(ciou)) { v_box = 1.f - ciou; v_nv = 1.f; }
            v_cls = csum;
            float ox = pred[4];
            v_obj = bce_f(ox, 1.f) - 0.5f * bce_f(ox, 0.f);
        }
    }

    #pragma unroll
    for (int off = 32; off; off >>= 1) {
        v_box += __shfl_down(v_box, off);
        v_nv  += __shfl_down(v_nv,  off);
        v_cls += __shfl_down(v_cls, off);
        v_obj += __shfl_down(v_obj, off);
    }
    if (lane == 0) { red[0][wv] = v_box; red[1][wv] = v_nv; red[2][wv] = v_cls; red[3][wv] = v_obj; }
    __syncthreads();
    if (t == 0) {
        float* slot = ws_f + POS_SLOT(pbid);
        slot[0] = red[0][0] + red[0][1] + red[0][2] + red[0][3];
        slot[1] = red[1][0] + red[1][1] + red[1][2] + red[1][3];
        slot[2] = red[2][0] + red[2][1] + red[2][2] + red[2][3];
        slot[3] = red[3][0] + red[3][1] + red[3][2] + red[3][3];
    }
}

__global__ __launch_bounds__(256) void final_kernel(const float* ws_f, const int* ws_i,
                                                    float* __restrict__ out)
{
    const int t = threadIdx.x;
    const int lane = t & 63, wv = t >> 6;
    __shared__ float sc[3][6];   // per scale: box, nv, cls, obj_corr, np, obj_base

    if (wv < 3) {
        const int s = wv;
        float box = 0.f, nv = 0.f, cls = 0.f, oc = 0.f, np = 0.f, ob = 0.f;
        // obj slots for this scale
        const int ocnt  = (s == 0) ? 128 : (s == 1) ? 32 : 8;
        const int obase = (s == 0) ? 0   : (s == 1) ? 128 : 160;
        for (int i = lane; i < ocnt; i += 64) ob += ws_f[OBJ_SLOT(obase + i)];
        // pos slots for this scale: 16 batches x 6 sub-blocks
        for (int i = lane; i < 96; i += 64) {
            int m = i / 6, sub = i % 6;
            const float* ps = ws_f + POS_SLOT((3 * m + s) * 6 + sub);
            box += ps[0]; nv += ps[1]; cls += ps[2]; oc += ps[3];
        }
        // winner counts from assign slots
        if (lane < 16) np = (float)ws_i[A_SLOT(lane * 3 + s)];
        #pragma unroll
        for (int off = 32; off; off >>= 1) {
            box += __shfl_down(box, off);
            nv  += __shfl_down(nv,  off);
            cls += __shfl_down(cls, off);
            oc  += __shfl_down(oc,  off);
            np  += __shfl_down(np,  off);
            ob  += __shfl_down(ob,  off);
        }
        if (lane == 0) {
            sc[s][0] = box; sc[s][1] = nv; sc[s][2] = cls;
            sc[s][3] = oc;  sc[s][4] = np; sc[s][5] = ob;
        }
    }
    __syncthreads();
    if (t == 0) {
        float bl = 0.f, ol = 0.f, cl = 0.f;
        int tv = 0;
        for (int s = 0; s < 3; ++s) {
            int Wd = 80 >> s;
            int total = BATCH * NA * Wd * Wd;
            float nv = sc[s][1], np = sc[s][4];
            bl += sc[s][0] / fmaxf(nv, 1.f);
            float wsum = np + 0.5f * ((float)total - np);
            ol += (sc[s][5] + sc[s][3]) / (wsum + 1e-6f);
            cl += sc[s][2] / fmaxf(np * (float)NC, 1.f);
            tv += (int)nv;
        }
        if (tv > 0) { bl /= 3.f; cl /= 3.f; }
        ol /= 3.f;
        float total = 0.15f * bl + 5.0f * ol + 0.5f * cl;
        out[0] = isfinite(total) ? total : 0.f;
    }
}

extern "C" void kernel_launch(void* const* d_in, const int* in_sizes, int n_in,
                              void* d_out, int out_size, void* d_ws, size_t ws_size,
                              hipStream_t stream) {
    const float* p0  = (const float*)d_in[0];
    const float* p1  = (const float*)d_in[1];
    const float* p2  = (const float*)d_in[2];
    const float* a0  = (const float*)d_in[3];
    const float* a1  = (const float*)d_in[4];
    const float* a2  = (const float*)d_in[5];
    const float* gtb = (const float*)d_in[6];
    const int*   gtl = (const int*)d_in[7];

    assign_kernel<<<ASSIGN_GRID, 128, 0, stream>>>(gtb, a0, a1, a2, (int*)d_ws);
    loss_kernel<<<LOSS_GRID, 256, 0, stream>>>(
        p0, p1, p2, a0, a1, a2, gtb, gtl, (float*)d_ws, (const int*)d_ws);
    final_kernel<<<1, 256, 0, stream>>>((const float*)d_ws, (const int*)d_ws, (float*)d_out);
}

// Round 11
// 22.795 us; speedup vs baseline: 1.9452x; 1.1522x over previous
//
#include <hip/hip_runtime.h>
#include <math.h>

#define NC 80
#define NA 3
#define BATCH 16
#define NGT 32
#define IOU_THR 0.5f
#define FEPS 1e-7f

#define OBJ_BLOCKS 168            // 128(s0)+32(s1)+8(s2) x 2400 cells grid-stride (R2-exact)
#define POS_BLOCKS 288            // 6 sub-blocks per (b,si); each inlines the assignment
#define LOSS_GRID (OBJ_BLOCKS + POS_BLOCKS)   // 456

// ws word layout — every slot written unconditionally each call (poison-proof);
// one exclusive 128B line per writer block (per-XCD L2s not cross-coherent).
//   OBJ_SLOT(j): obj partial
//   POS_SLOT(j): box, nv, cls, obj_corr, wn
#define OBJ_SLOT(j) (32 * (j))                 // 168*32 = 5376 words
#define POS_SLOT(j) (5376 + 32 * (j))          // +288*32 -> 14592 words (58KB)

__device__ __forceinline__ float bce_f(float x, float t) {
    return fmaxf(x, 0.f) - x * t + log1pf(expf(-fabsf(x)));
}

__global__ __launch_bounds__(256) void loss_kernel(
    const float* __restrict__ p0, const float* __restrict__ p1, const float* __restrict__ p2,
    const float* __restrict__ a0, const float* __restrict__ a1, const float* __restrict__ a2,
    const float* __restrict__ gt_boxes, const int* __restrict__ gt_labels,
    float* ws_f)
{
    const int bid = blockIdx.x;
    const int t = threadIdx.x;
    const int lane = t & 63, wv = t >> 6;
    __shared__ float red[4][4];

    if (bid < OBJ_BLOCKS) {
        // ---- noobj base sweep (R2-exact): 2400 cells grid-stride ----
        int blk_local; const float* p;
        if (bid < 128)      { blk_local = bid;       p = p0; }
        else if (bid < 160) { blk_local = bid - 128; p = p1; }
        else                { blk_local = bid - 160; p = p2; }
        int base_e = blk_local * 2400;
        float acc = 0.f;
        #pragma unroll 2
        for (int i = t; i < 2400; i += 256) {
            float x = p[(size_t)(base_e + i) * (5 + NC) + 4];
            acc += 0.5f * bce_f(x, 0.f);
        }
        #pragma unroll
        for (int off = 32; off; off >>= 1) acc += __shfl_down(acc, off);
        if (lane == 0) red[0][wv] = acc;
        __syncthreads();
        if (t == 0)
            ws_f[OBJ_SLOT(bid)] = red[0][0] + red[0][1] + red[0][2] + red[0][3];
        return;
    }

    // ---- positive-cell losses with INLINED assignment (6x redundant, parallel) ----
    const int pbid = bid - OBJ_BLOCKS;     // [0, 288)
    const int g48 = pbid / 6;              // (b*3 + si)
    const int sub = pbid % 6;
    const int si = g48 % 3;
    const int b  = g48 / 3;
    const int W  = 80 >> si;
    const int HW = W * W;
    const float s = (float)(8 << si);
    const float* p    = (si == 0) ? p0 : (si == 1) ? p1 : p2;
    const float* anch = (si == 0) ? a0 : (si == 1) ? a1 : a2;

    __shared__ float gtb[NGT][4];
    __shared__ int   gflat[NGT];
    __shared__ float giou[NA][NGT];
    __shared__ float gcand[NA][NGT];
    __shared__ unsigned char gposm[NA][NGT];
    __shared__ unsigned char gisb[NA][NGT];
    __shared__ int wlist[NA * NGT];
    __shared__ int wcnt[4];
    __shared__ int s_wn;

    if (t < 128) gtb[t >> 2][t & 3] = gt_boxes[b * NGT * 4 + t];
    __syncthreads();

    if (t < NGT) {
        float x1 = gtb[t][0], y1 = gtb[t][1], x2 = gtb[t][2], y2 = gtb[t][3];
        float gcx = (x1 + x2) * 0.5f, gcy = (y1 + y2) * 0.5f;
        int gx = (int)(gcx / s); gx = min(max(gx, 0), W - 1);
        int gy = (int)(gcy / s); gy = min(max(gy, 0), W - 1);
        gflat[t] = gy * W + gx;
    }
    __syncthreads();

    if (t < NA * NGT) {
        int a = t >> 5, n = t & 31;
        int flat = gflat[n];
        const float* ap = anch + ((size_t)a * HW + flat) * 4;
        float acx = ap[0], acy = ap[1], aw = ap[2], ah = ap[3];
        float ax1 = acx - aw * 0.5f, ay1 = acy - ah * 0.5f;
        float ax2 = acx + aw * 0.5f, ay2 = acy + ah * 0.5f;
        float x1 = gtb[n][0], y1 = gtb[n][1], x2 = gtb[n][2], y2 = gtb[n][3];
        float iw = fmaxf(fminf(x2, ax2) - fmaxf(x1, ax1), 0.f);
        float ih = fmaxf(fminf(y2, ay2) - fmaxf(y1, ay1), 0.f);
        float inter = iw * ih;
        float a_gt = (x2 - x1) * (y2 - y1);
        float a_an = aw * ah;
        giou[a][n] = inter / (a_gt + a_an - inter + FEPS);
    }
    __syncthreads();

    if (t < NA * NGT) {
        int a = t >> 5, n = t & 31;
        float i0 = giou[0][n], i1 = giou[1][n], i2 = giou[2][n];
        bool has = (i0 > IOU_THR) || (i1 > IOU_THR) || (i2 > IOU_THR);
        int amax = 0; float bv = i0;                // first-max like jnp.argmax
        if (i1 > bv) { bv = i1; amax = 1; }
        if (i2 > bv) { bv = i2; amax = 2; }
        float iou = giou[a][n];
        bool ps = has ? (iou > IOU_THR) : (a == amax);
        gposm[a][n] = ps ? 1 : 0;
        gcand[a][n] = ps ? iou : -1.0f;
    }
    __syncthreads();

    if (t < NA * NGT) {
        int a = t >> 5, n = t & 31;
        int flat = gflat[n];
        float best = -1.0f;                         // scatter-max init
        for (int m = 0; m < NGT; ++m)
            if (gflat[m] == flat) best = fmaxf(best, gcand[a][m]);
        gisb[a][n] = (gposm[a][n] && gcand[a][n] >= best) ? 1 : 0;
    }
    __syncthreads();

    // winner detection + ballot-compacted list (no atomics)
    int win = 0, pack = 0;
    if (t < NA * NGT) {
        int a = t >> 5, n = t & 31;
        if (gisb[a][n]) {
            int flat = gflat[n];
            bool first = true;                      // win = min gt index among isb
            for (int m = 0; m < n; ++m)
                if (gflat[m] == flat && gisb[a][m]) { first = false; break; }
            if (first) { win = 1; pack = flat | (a << 13) | (n << 19); }
        }
    }
    unsigned long long mask = __ballot(win);
    if (lane == 0) wcnt[wv] = (int)__popcll(mask);
    __syncthreads();
    if (win) {
        int base = 0;
        for (int w2 = 0; w2 < wv; ++w2) base += wcnt[w2];
        int idx = base + (int)__popcll(mask & ((1ull << lane) - 1ull));
        wlist[idx] = pack;
    }
    if (t == 0) s_wn = wcnt[0] + wcnt[1] + wcnt[2] + wcnt[3];
    __syncthreads();
    const int wn = s_wn;

    // ---- this block's share: cells [sub*16, sub*16+16), 16 lanes/cell (R2-exact) ----
    const int g16 = t >> 4, l16 = t & 15;
    const int cell = sub * 16 + g16;
    float v_box = 0.f, v_nv = 0.f, v_cls = 0.f, v_obj = 0.f;
    if (cell < wn) {
        int e = wlist[cell];
        int flat = e & 0x1FFF;
        int a = (e >> 13) & 3;
        int n = (e >> 19) & 31;
        const float* pred = p + (size_t)((b * NA + a) * HW + flat) * (5 + NC);

        // cls BCE: 5 coalesced channels per lane
        int label = gt_labels[b * NGT + n];
        float csum = 0.f;
        #pragma unroll
        for (int jj = 0; jj < 5; ++jj) {
            int c = l16 + 16 * jj;
            float x = pred[5 + c];
            csum += bce_f(x, (c == label) ? 1.f : 0.f);
        }
        #pragma unroll
        for (int m = 8; m; m >>= 1) csum += __shfl_xor(csum, m);

        // decode + ciou (redundant on 16 lanes; lane 0 contributes)
        const float* ap = anch + ((size_t)a * HW + flat) * 4;
        float acx = ap[0], acy = ap[1], aw = ap[2], ah = ap[3];
        float s0 = 1.f / (1.f + expf(-pred[0]));
        float s1 = 1.f / (1.f + expf(-pred[1]));
        float s2 = 1.f / (1.f + expf(-pred[2]));
        float s3 = 1.f / (1.f + expf(-pred[3]));
        float cx = acx + (s0 * 2.f - 0.5f) * s;
        float cy = acy + (s1 * 2.f - 0.5f) * s;
        float pw = aw * (s2 * 2.f) * (s2 * 2.f);
        float ph = ah * (s3 * 2.f) * (s3 * 2.f);
        float b1x1 = cx - pw * 0.5f, b1y1 = cy - ph * 0.5f;
        float b1x2 = cx + pw * 0.5f, b1y2 = cy + ph * 0.5f;
        float b2x1 = gtb[n][0], b2y1 = gtb[n][1];
        float b2x2 = gtb[n][2], b2y2 = gtb[n][3];

        float w1 = b1x2 - b1x1, h1 = b1y2 - b1y1;
        float w2 = b2x2 - b2x1, h2 = b2y2 - b2y1;
        float iw = fmaxf(fminf(b1x2, b2x2) - fmaxf(b1x1, b2x1), 0.f);
        float ih = fmaxf(fminf(b1y2, b2y2) - fmaxf(b1y1, b2y1), 0.f);
        float inter = iw * ih;
        float uni = w1 * h1 + w2 * h2 - inter + FEPS;
        float iou = inter / uni;
        float cw = fmaxf(b1x2, b2x2) - fminf(b1x1, b2x1);
        float ch = fmaxf(b1y2, b2y2) - fminf(b1y1, b2y1);
        float c2 = cw * cw + ch * ch + FEPS;
        float dx = b2x1 + b2x2 - b1x1 - b1x2;
        float dy = b2y1 + b2y2 - b1y1 - b1y2;
        float rho2 = (dx * dx + dy * dy) * 0.25f;
        const float PI = 3.14159265358979323846f;
        float dv = atanf(w2 / (h2 + FEPS)) - atanf(w1 / (h1 + FEPS));
        float v = (4.f / (PI * PI)) * dv * dv;
        float alpha = v / (v - iou + (1.f + FEPS));
        float ciou = iou - rho2 / c2 - alpha * v;

        if (l16 == 0) {
            if (isfinite(ciou)) { v_box = 1.f - ciou; v_nv = 1.f; }
            v_cls = csum;
            float ox = pred[4];
            v_obj = bce_f(ox, 1.f) - 0.5f * bce_f(ox, 0.f);
        }
    }

    #pragma unroll
    for (int off = 32; off; off >>= 1) {
        v_box += __shfl_down(v_box, off);
        v_nv  += __shfl_down(v_nv,  off);
        v_cls += __shfl_down(v_cls, off);
        v_obj += __shfl_down(v_obj, off);
    }
    if (lane == 0) { red[0][wv] = v_box; red[1][wv] = v_nv; red[2][wv] = v_cls; red[3][wv] = v_obj; }
    __syncthreads();
    if (t == 0) {
        float* slot = ws_f + POS_SLOT(pbid);
        slot[0] = red[0][0] + red[0][1] + red[0][2] + red[0][3];
        slot[1] = red[1][0] + red[1][1] + red[1][2] + red[1][3];
        slot[2] = red[2][0] + red[2][1] + red[2][2] + red[2][3];
        slot[3] = red[3][0] + red[3][1] + red[3][2] + red[3][3];
        slot[4] = (float)wn;
    }
}

__global__ __launch_bounds__(256) void final_kernel(const float* ws_f,
                                                    float* __restrict__ out)
{
    const int t = threadIdx.x;
    const int lane = t & 63, wv = t >> 6;
    __shared__ float sc[3][6];   // per scale: box, nv, cls, obj_corr, np, obj_base

    if (wv < 3) {
        const int s = wv;
        float box = 0.f, nv = 0.f, cls = 0.f, oc = 0.f, np = 0.f, ob = 0.f;
        // obj slots for this scale
        const int ocnt  = (s == 0) ? 128 : (s == 1) ? 32 : 8;
        const int obase = (s == 0) ? 0   : (s == 1) ? 128 : 160;
        for (int i = lane; i < ocnt; i += 64) ob += ws_f[OBJ_SLOT(obase + i)];
        // pos slots for this scale: 16 batches x 6 sub-blocks; np from sub==0
        for (int i = lane; i < 96; i += 64) {
            int m = i / 6, sub = i % 6;
            const float* ps = ws_f + POS_SLOT((3 * m + s) * 6 + sub);
            box += ps[0]; nv += ps[1]; cls += ps[2]; oc += ps[3];
            if (sub == 0) np += ps[4];
        }
        #pragma unroll
        for (int off = 32; off; off >>= 1) {
            box += __shfl_down(box, off);
            nv  += __shfl_down(nv,  off);
            cls += __shfl_down(cls, off);
            oc  += __shfl_down(oc,  off);
            np  += __shfl_down(np,  off);
            ob  += __shfl_down(ob,  off);
        }
        if (lane == 0) {
            sc[s][0] = box; sc[s][1] = nv; sc[s][2] = cls;
            sc[s][3] = oc;  sc[s][4] = np; sc[s][5] = ob;
        }
    }
    __syncthreads();
    if (t == 0) {
        float bl = 0.f, ol = 0.f, cl = 0.f;
        int tv = 0;
        for (int s = 0; s < 3; ++s) {
            int Wd = 80 >> s;
            int total = BATCH * NA * Wd * Wd;
            float nv = sc[s][1], np = sc[s][4];
            bl += sc[s][0] / fmaxf(nv, 1.f);
            float wsum = np + 0.5f * ((float)total - np);
            ol += (sc[s][5] + sc[s][3]) / (wsum + 1e-6f);
            cl += sc[s][2] / fmaxf(np * (float)NC, 1.f);
            tv += (int)nv;
        }
        if (tv > 0) { bl /= 3.f; cl /= 3.f; }
        ol /= 3.f;
        float total = 0.15f * bl + 5.0f * ol + 0.5f * cl;
        out[0] = isfinite(total) ? total : 0.f;
    }
}

extern "C" void kernel_launch(void* const* d_in, const int* in_sizes, int n_in,
                              void* d_out, int out_size, void* d_ws, size_t ws_size,
                              hipStream_t stream) {
    const float* p0  = (const float*)d_in[0];
    const float* p1  = (const float*)d_in[1];
    const float* p2  = (const float*)d_in[2];
    const float* a0  = (const float*)d_in[3];
    const float* a1  = (const float*)d_in[4];
    const float* a2  = (const float*)d_in[5];
    const float* gtb = (const float*)d_in[6];
    const int*   gtl = (const int*)d_in[7];

    loss_kernel<<<LOSS_GRID, 256, 0, stream>>>(
        p0, p1, p2, a0, a1, a2, gtb, gtl, (float*)d_ws);
    final_kernel<<<1, 256, 0, stream>>>((const float*)d_ws, (float*)d_out);
}